// Round 11
// baseline (76.336 us; speedup 1.0000x reference)
//
#include <hip/hip_runtime.h>

#define M_DIM 64
#define K_DIM 8192
#define N_DIM 8192
#define QB 32
#define NT 256                     // cols per block (64 per wave)
#define KC 32                      // k per stage == one quant block
#define SPLITS 16
#define KSPLIT (K_DIM / SPLITS)    // 512
#define NSTAGE (KSPLIT / KC)       // 16 (even, ping-pong)

typedef __attribute__((ext_vector_type(8))) short short8;     // MFMA A/B frag
typedef __attribute__((ext_vector_type(8))) unsigned short ushort8;
typedef __attribute__((ext_vector_type(4))) float f32x4;
typedef __attribute__((ext_vector_type(4))) int i32x4;
typedef __attribute__((ext_vector_type(4))) unsigned int u32x4;

static_assert(NSTAGE % 2 == 0 && NSTAGE * KC == KSPLIT, "tiling");

// f32 -> bf16 round-to-nearest-even
__device__ __forceinline__ unsigned short f2bf(float f) {
    unsigned u = __builtin_bit_cast(unsigned, f);
    u += 0x7fffu + ((u >> 16) & 1u);
    return (unsigned short)(u >> 16);
}

// Fused prep: blocks [0,256) convert x f32->bf16 into ws (1MB, L2-resident);
// blocks [256,768) overwrite out with bias (clears poison; qgemm atomicAdds
// on top). One launch instead of two.
__global__ __launch_bounds__(256) void prep(const float* __restrict__ x,
                                            unsigned short* __restrict__ xb,
                                            const float* __restrict__ bias,
                                            float* __restrict__ out) {
    const int b = blockIdx.x;
    if (b < 256) {
        int i = (b * 256 + threadIdx.x) * 8;
        f32x4 a = *(const f32x4*)(x + i);
        f32x4 c = *(const f32x4*)(x + i + 4);
        ushort8 o;
        #pragma unroll
        for (int e = 0; e < 4; ++e) { o[e] = f2bf(a[e]); o[4 + e] = f2bf(c[e]); }
        *(ushort8*)(xb + i) = o;
    } else {
        int i = ((b - 256) * 256 + threadIdx.x) * 4;
        *(f32x4*)(out + i) = *(const f32x4*)(bias + (i & (N_DIM - 1)));
    }
}

// Fallback-path bias clear (when ws too small for xb).
__global__ __launch_bounds__(256) void bias_init(const float* __restrict__ bias,
                                                 float* __restrict__ out) {
    int i = (blockIdx.x * 256 + threadIdx.x) * 4;
    *(f32x4*)(out + i) = *(const f32x4*)(bias + (i & (N_DIM - 1)));
}

// R11: the CLEAN 1KB-granule experiment. Weight loads are dwordx4 over a
// 256-col tile: one wave-instruction = 64 lanes x 16B = 1KB contiguous of a
// single k-row (4x the granule of the ~60us plateau kernels). Wave w owns
// k-rows 8w..8w+7 of the stage, so each lane holds 8 CONTIGUOUS ks of 4
// cols -> direct ds_write_b128 per col into a [col][k] tile, and both
// fragment paths stay b128 (<=2-way conflicts). Everything else is the
// validated R1 recipe: LDS-staged x, one __syncthreads per stage, 2-buffer
// ping-pong, 1-deep prefetch, atomic epilogue, validated layouts.
template <bool XBF>
__global__ __launch_bounds__(256, 2) void qgemm(
    const float* __restrict__ x,             // [M][K] f32 (fallback)
    const unsigned short* __restrict__ xb,   // [M][K] bf16 (main)
    const float* __restrict__ scales,        // [K/QB][N]
    const float* __restrict__ zeros,         // [K/QB][N]
    const int*   __restrict__ qw,            // [K][N], 0..255
    float*       __restrict__ out)           // [M][N]
{
    // lw: [col 256][k 32] bf16, row stride 40 shorts = 80B (16B-aligned for
    // b128; 20 dwords/row -> frag-read banks (20*lm+4*q)&31 = 2-way max).
    // lx: [m 64][k 32] bf16, same stride family.
    __shared__ unsigned short lw[2][NT][40];
    __shared__ unsigned short lx[2][M_DIM][40];

    const int tid  = threadIdx.x;
    const int lane = tid & 63;
    const int w    = tid >> 6;      // wave: k-rows 8w..8w+7; C-cols [64w,64w+64)
    const int q    = lane >> 4;     // k-slot / C row-quarter
    const int lm   = lane & 15;

    const int n0 = blockIdx.x * NT;
    const int k0 = blockIdx.y * KSPLIT;

    const int*   qp = qw     + (size_t)k0 * N_DIM        + n0 + 4 * lane;
    const float* sp = scales + (size_t)(k0 >> 5) * N_DIM + n0 + 4 * lane;
    const float* zp = zeros  + (size_t)(k0 >> 5) * N_DIM + n0 + 4 * lane;

    const int xrow = tid >> 2;      // x staging: row 0..63
    const int xq   = tid & 3;       // 8 ks per thread

    // ping-pong stage registers
    i32x4 qvA[8], qvB[8];           // 8 rows x 4 cols each
    f32x4 scA, zcA, scB, zcB;
    u32x4 xvA, xvB;                 // 8 bf16 (XBF)
    f32x4 xfA[2], xfB[2];           // 8 f32 (fallback)

#define LOADS(S, T)                                                           \
    do {                                                                      \
        const int* _p = qp + (size_t)(T) * KC * N_DIM;                        \
        _Pragma("unroll")                                                     \
        for (int i = 0; i < 8; ++i)                                           \
            qv##S[i] = *(const i32x4*)(_p + (size_t)(8 * w + i) * N_DIM);     \
        sc##S = *(const f32x4*)(sp + (size_t)(T) * N_DIM);                    \
        zc##S = *(const f32x4*)(zp + (size_t)(T) * N_DIM);                    \
        if (XBF) {                                                            \
            xv##S = *(const u32x4*)(xb + (size_t)xrow * K_DIM                 \
                                    + (k0 + (T) * KC) + 8 * xq);              \
        } else {                                                              \
            const float* _xp = x + (size_t)xrow * K_DIM                       \
                                 + (k0 + (T) * KC) + 8 * xq;                  \
            xf##S[0] = *(const f32x4*)_xp;                                    \
            xf##S[1] = *(const f32x4*)(_xp + 4);                              \
        }                                                                     \
    } while (0)

#define BODY(S, CUR)                                                          \
    do {                                                                      \
        const f32x4 _nz = -sc##S * zc##S;                                     \
        _Pragma("unroll")                                                     \
        for (int j = 0; j < 3 + 1; ++j) {                                     \
            unsigned hh[4];                                                   \
            _Pragma("unroll")                                                 \
            for (int p = 0; p < 4; ++p) {                                     \
                unsigned short h0 =                                           \
                    f2bf(fmaf((float)qv##S[2 * p][j],     sc##S[j], _nz[j])); \
                unsigned short h1 =                                           \
                    f2bf(fmaf((float)qv##S[2 * p + 1][j], sc##S[j], _nz[j])); \
                hh[p] = (unsigned)h0 | ((unsigned)h1 << 16);                  \
            }                                                                 \
            *(u32x4*)&lw[CUR][4 * lane + j][8 * w] =                          \
                (u32x4){hh[0], hh[1], hh[2], hh[3]};                          \
        }                                                                     \
        if (XBF) {                                                            \
            *(u32x4*)&lx[CUR][xrow][8 * xq] = xv##S;                          \
        } else {                                                              \
            ushort8 xw;                                                       \
            _Pragma("unroll")                                                 \
            for (int e = 0; e < 4; ++e) {                                     \
                xw[e]     = f2bf(xf##S[0][e]);                                \
                xw[4 + e] = f2bf(xf##S[1][e]);                                \
            }                                                                 \
            *(ushort8*)&lx[CUR][xrow][8 * xq] = xw;                           \
        }                                                                     \
    } while (0)

#define MM(CUR)                                                               \
    do {                                                                      \
        short8 bf[4], af[4];                                                  \
        _Pragma("unroll")                                                     \
        for (int g = 0; g < 4; ++g)                                           \
            bf[g] = *(const short8*)&lw[CUR][64 * w + 16 * g + lm][8 * q];    \
        _Pragma("unroll")                                                     \
        for (int r = 0; r < 4; ++r)                                           \
            af[r] = *(const short8*)&lx[CUR][16 * r + lm][8 * q];             \
        _Pragma("unroll")                                                     \
        for (int g = 0; g < 4; ++g)                                           \
            _Pragma("unroll")                                                 \
            for (int r = 0; r < 4; ++r)                                       \
                acc[g][r] = __builtin_amdgcn_mfma_f32_16x16x32_bf16(          \
                    af[r], bf[g], acc[g][r], 0, 0, 0);                        \
    } while (0)

    f32x4 acc[4][4];                // [colfrag g][rowfrag r]
    #pragma unroll
    for (int a = 0; a < 4; ++a)
        #pragma unroll
        for (int b = 0; b < 4; ++b) acc[a][b] = (f32x4){0.f, 0.f, 0.f, 0.f};

    LOADS(A, 0);

    for (int t = 0; t < NSTAGE; t += 2) {
        LOADS(B, t + 1);            // in flight across barrier
        BODY(A, 0);
        __syncthreads();
        MM(0);
        if (t + 2 < NSTAGE) LOADS(A, t + 2);
        BODY(B, 1);
        __syncthreads();
        MM(1);
    }

#undef LOADS
#undef BODY
#undef MM

    // epilogue: C layout col=lane&15, row=4*(lane>>4)+e (validated)
    #pragma unroll
    for (int g = 0; g < 4; ++g) {
        const int cn = n0 + 64 * w + 16 * g + lm;
        #pragma unroll
        for (int r = 0; r < 4; ++r) {
            const int m = 16 * r + 4 * q;
            #pragma unroll
            for (int e = 0; e < 4; ++e)
                atomicAdd(out + (size_t)(m + e) * N_DIM + cn, acc[g][r][e]);
        }
    }
}

extern "C" void kernel_launch(void* const* d_in, const int* in_sizes, int n_in,
                              void* d_out, int out_size, void* d_ws, size_t ws_size,
                              hipStream_t stream) {
    const float* x      = (const float*)d_in[0];
    const float* scales = (const float*)d_in[1];
    const float* zeros  = (const float*)d_in[2];
    const float* bias   = (const float*)d_in[3];
    const int*   qw     = (const int*)d_in[4];
    float* out = (float*)d_out;
    unsigned short* xbf = (unsigned short*)d_ws;

    const bool use_xbf = ws_size >= (size_t)M_DIM * K_DIM * 2;

    if (use_xbf) {
        prep<<<dim3(768), 256, 0, stream>>>(x, xbf, bias, out);
        qgemm<true><<<dim3(N_DIM / NT, SPLITS), 256, 0, stream>>>(
            x, xbf, scales, zeros, qw, out);
    } else {
        bias_init<<<dim3((M_DIM * N_DIM) / 1024), 256, 0, stream>>>(bias, out);
        qgemm<false><<<dim3(N_DIM / NT, SPLITS), 256, 0, stream>>>(
            x, nullptr, scales, zeros, qw, out);
    }
}

// Round 12
// 59.359 us; speedup vs baseline: 1.2860x; 1.2860x over previous
//
#include <hip/hip_runtime.h>

#define M_DIM 64
#define K_DIM 8192
#define N_DIM 8192
#define QB 32
#define NT 64               // N columns per block
#define KC 64               // K per stage (2 quant blocks)
#define SPLITS 4
#define KSPLIT (K_DIM / SPLITS)    // 2048
#define NSTAGE (KSPLIT / KC)       // 32

typedef __attribute__((ext_vector_type(8))) short short8;     // MFMA A/B frag
typedef __attribute__((ext_vector_type(8))) unsigned short ushort8;
typedef __attribute__((ext_vector_type(4))) float f32x4;

static_assert(NSTAGE * KC == KSPLIT, "split must tile");

// f32 -> bf16 round-to-nearest-even
__device__ __forceinline__ unsigned short f2bf(float f) {
    unsigned u = __builtin_bit_cast(unsigned, f);
    u += 0x7fffu + ((u >> 16) & 1u);
    return (unsigned short)(u >> 16);
}

// Fallback path only: clears poison with bias; qgemm<false> atomicAdds on top.
__global__ __launch_bounds__(256) void bias_init(const float* __restrict__ bias,
                                                 float* __restrict__ out) {
    int i = (blockIdx.x * 256 + threadIdx.x) * 4;
    *(f32x4*)(out + i) = *(const f32x4*)(bias + (i & (N_DIM - 1)));
}

// R1's validated 60.2us kernel, unchanged except the epilogue:
// PART=true stores per-split partials to ws (coalesced, no RMW) instead of
// 2.1M atomicAdds. Everything else byte-identical to the plateau champion.
template <bool PART>
__global__ __launch_bounds__(256, 2) void qgemm(
    const float* __restrict__ x,       // [M][K]
    const float* __restrict__ scales,  // [K/QB][N]
    const float* __restrict__ zeros,   // [K/QB][N]
    const int*   __restrict__ qw,      // [K][N], values 0..255
    float*       __restrict__ outp)    // PART ? [SPLITS][M][N] : [M][N]
{
    __shared__ unsigned short lq[2][NT][72];   // [n][k] bf16, 144B rows
    __shared__ unsigned short lx[2][M_DIM][72];

    const int tid  = threadIdx.x;
    const int lane = tid & 63;
    const int w    = tid >> 6;          // wave 0..3, owns cols [16w,16w+16)

    const int n0 = blockIdx.x * NT;
    const int k0 = blockIdx.y * KSPLIT;

    const int qn   = n0 + lane;         // this thread's weight column
    const int xrow = tid >> 2;          // x staging: row 0..63
    const int xcol = (tid & 3) * 16;    // 16 k's per thread

    int   qv[16];
    float sv0, sv1, zv0, zv1;
    f32x4 xv[4];

    auto load_stage = [&](int kk) {
        #pragma unroll
        for (int s = 0; s < 4; ++s)
            #pragma unroll
            for (int j = 0; j < 4; ++j)
                qv[s * 4 + j] = qw[(size_t)(kk + 16 * s + 4 * w + j) * N_DIM + qn];
        const int b0 = kk >> 5;
        sv0 = scales[(size_t)b0 * N_DIM + qn];
        sv1 = scales[(size_t)(b0 + 1) * N_DIM + qn];
        zv0 = zeros[(size_t)b0 * N_DIM + qn];
        zv1 = zeros[(size_t)(b0 + 1) * N_DIM + qn];
        #pragma unroll
        for (int i = 0; i < 4; ++i)
            xv[i] = *(const f32x4*)(x + (size_t)xrow * K_DIM + kk + xcol + 4 * i);
    };

    load_stage(k0);

    f32x4 acc[4];
    #pragma unroll
    for (int r = 0; r < 4; ++r) acc[r] = (f32x4){0.f, 0.f, 0.f, 0.f};

    for (int t = 0; t < NSTAGE; ++t) {
        const int cur = t & 1;

        const float nz0 = -sv0 * zv0, nz1 = -sv1 * zv1;
        const float s0r = sv0, s1r = sv1;
        uint2 qd[4];
        #pragma unroll
        for (int s = 0; s < 4; ++s) {
            const float sc = (s < 2) ? s0r : s1r;
            const float nz = (s < 2) ? nz0 : nz1;
            unsigned short h0 = f2bf(fmaf((float)qv[s * 4 + 0], sc, nz));
            unsigned short h1 = f2bf(fmaf((float)qv[s * 4 + 1], sc, nz));
            unsigned short h2 = f2bf(fmaf((float)qv[s * 4 + 2], sc, nz));
            unsigned short h3 = f2bf(fmaf((float)qv[s * 4 + 3], sc, nz));
            qd[s].x = (unsigned)h0 | ((unsigned)h1 << 16);
            qd[s].y = (unsigned)h2 | ((unsigned)h3 << 16);
        }
        ushort8 xw0, xw1;
        #pragma unroll
        for (int e = 0; e < 4; ++e) {
            xw0[e]     = f2bf(xv[0][e]);
            xw0[4 + e] = f2bf(xv[1][e]);
            xw1[e]     = f2bf(xv[2][e]);
            xw1[4 + e] = f2bf(xv[3][e]);
        }

        if (t + 1 < NSTAGE) load_stage(k0 + (t + 1) * KC);

        #pragma unroll
        for (int s = 0; s < 4; ++s)
            *(uint2*)&lq[cur][lane][16 * s + 4 * w] = qd[s];
        *(ushort8*)&lx[cur][xrow][xcol]     = xw0;
        *(ushort8*)&lx[cur][xrow][xcol + 8] = xw1;

        __syncthreads();

        #pragma unroll
        for (int c = 0; c < 2; ++c) {
            const short8 bf = *(const short8*)&lq[cur][16 * w + (lane & 15)]
                                                [32 * c + 8 * (lane >> 4)];
            #pragma unroll
            for (int r = 0; r < 4; ++r) {
                const short8 af = *(const short8*)&lx[cur][16 * r + (lane & 15)]
                                                    [32 * c + 8 * (lane >> 4)];
                acc[r] = __builtin_amdgcn_mfma_f32_16x16x32_bf16(af, bf, acc[r], 0, 0, 0);
            }
        }
    }

    // epilogue: C layout col=lane&15, row=4*(lane>>4)+e (validated)
    const int cn = n0 + 16 * w + (lane & 15);
    if (PART) {
        float* po = outp + (size_t)blockIdx.y * (M_DIM * (size_t)N_DIM);
        #pragma unroll
        for (int r = 0; r < 4; ++r) {
            const int m = 16 * r + 4 * (lane >> 4);
            #pragma unroll
            for (int e = 0; e < 4; ++e)
                po[(size_t)(m + e) * N_DIM + cn] = acc[r][e];
        }
    } else {
        #pragma unroll
        for (int r = 0; r < 4; ++r) {
            const int m = 16 * r + 4 * (lane >> 4);
            #pragma unroll
            for (int e = 0; e < 4; ++e)
                atomicAdd(outp + (size_t)(m + e) * N_DIM + cn, acc[r][e]);
        }
    }
}

// out = bias + sum of SPLITS partials. Fully overwrites d_out every call
// (clears poison). 10MB traffic, fully coalesced, L2-warm partials.
__global__ __launch_bounds__(256) void reduce_bias(const float* __restrict__ part,
                                                   const float* __restrict__ bias,
                                                   float* __restrict__ out) {
    int i = (blockIdx.x * 256 + threadIdx.x) * 4;
    f32x4 s = *(const f32x4*)(bias + (i & (N_DIM - 1)));
    #pragma unroll
    for (int sp = 0; sp < SPLITS; ++sp)
        s += *(const f32x4*)(part + (size_t)sp * (M_DIM * (size_t)N_DIM) + i);
    *(f32x4*)(out + i) = s;
}

extern "C" void kernel_launch(void* const* d_in, const int* in_sizes, int n_in,
                              void* d_out, int out_size, void* d_ws, size_t ws_size,
                              hipStream_t stream) {
    const float* x      = (const float*)d_in[0];
    const float* scales = (const float*)d_in[1];
    const float* zeros  = (const float*)d_in[2];
    const float* bias   = (const float*)d_in[3];
    const int*   qw     = (const int*)d_in[4];
    float* out  = (float*)d_out;
    float* part = (float*)d_ws;

    const size_t need = (size_t)SPLITS * M_DIM * N_DIM * sizeof(float);  // 8 MB

    if (ws_size >= need) {
        qgemm<true><<<dim3(N_DIM / NT, SPLITS), 256, 0, stream>>>(
            x, scales, zeros, qw, part);
        reduce_bias<<<dim3((M_DIM * N_DIM) / 1024), 256, 0, stream>>>(part, bias, out);
    } else {
        bias_init<<<dim3((M_DIM * N_DIM) / 1024), 256, 0, stream>>>(bias, out);
        qgemm<false><<<dim3(N_DIM / NT, SPLITS), 256, 0, stream>>>(
            x, scales, zeros, qw, out);
    }
}